// Round 15
// baseline (44.479 us; speedup 1.0000x reference)
//
#include <hip/hip_runtime.h>

#define HH 80
#define WW 80
#define IMG (HH * WW)             // 6400
#define NV ((HH - 1) * WW)        // 6320 vertical edge slots
#define NPTS (NV + HH * (WW - 1)) // 12640 edge slots per image
#define NPIX (2 * IMG)            // 12800
#define BIGF 1.0e10f
#define INVC 1.0e7f
#define EPSF 1e-8f
#define QSCALE 131072.0f          // 2^17 fixed point (exact-commutative sums)

// k_prep geometry: each set padded to 12800 slots = 50 blocks x 256 threads
#define SETPAD 12800
#define SBLOCKS (SETPAD / 256)    // 50 blocks per set
#define EXBLOCKS (4 * SBLOCKS)    // 200 extraction blocks
#define PXBLOCKS (NPIX / 256)     // 50 pixel blocks
#define PREPB (EXBLOCKS + PXBLOCKS) // 250

// k_min geometry (r11's proven tiling; LDS-free B-stream)
#define BLK 256                   // 4 waves
#define APT 8                     // A points per thread
#define ACHUNK (BLK * APT)        // 2048
#define ABLOCKS ((NPTS + ACHUNK - 1) / ACHUNK) // 7 worst case; 4 active
#define NSLICE 32

// k_fin geometry
#define FINB 32                   // 8 chunks per set
#define FTRIPS 7                  // ceil(NPTS / (8*256)) = 7 fixed trips

// scalar ws layout (each contended counter on its own 128-B line)
#define CNT_STRIDE 32             // ints; cnt[set] at d_ws + set*128
#define PIX_OFF 512
#define TICKET_OFF 640
#define SUM_OFF 768               // 4 x u64
#define SCALAR_BYTES 1024

typedef float f32x2 __attribute__((ext_vector_type(2)));

__device__ __forceinline__ long long wave_reduce_ll(long long v) {
#pragma unroll
  for (int o = 32; o > 0; o >>= 1) {
    int2 p = *(int2*)&v;
    p.x = __shfl_down(p.x, o, 64);
    p.y = __shfl_down(p.y, o, 64);
    v += *(long long*)&p;
  }
  return v;
}

// --------------------------------------------------------------- k_zero
__global__ void k_zero(unsigned int* __restrict__ w) {
  w[threadIdx.x] = 0u;   // 256 threads x 4 B = 1024 B (cnt, pix, ticket, sum_i)
}

// --------------------------------------------------------------- k_prep
// 250 blocks. minarr init + (blocks 0..199) zero-crossing extraction with
// block-aggregated atomic append (one atomicAdd per block, counters on
// separate cache lines) + (blocks 200..249) pixel loss in exact int64.
// Points stored as float4(x, y, x^2+y^2, 0) -- q2 precomputed once with the
// SAME fmaf expression k_min used, so the distance multiset is bit-identical.
__global__ void __launch_bounds__(256) k_prep(
    const float* __restrict__ pred, const float* __restrict__ gt,
    float4* __restrict__ pts, float* __restrict__ minarr,
    int* __restrict__ cnt, unsigned long long* __restrict__ pix_i) {
  __shared__ int wc[4], wo[4];
  __shared__ long long rl[4];
  int tid = threadIdx.x, lane = tid & 63, wid = tid >> 6;
  int gtid = blockIdx.x * 256 + tid;

  if (gtid < 4 * NPTS) minarr[gtid] = BIGF;

  if (blockIdx.x < EXBLOCKS) {
    int set = blockIdx.x / SBLOCKS;
    int idx = (blockIdx.x % SBLOCKS) * 256 + tid;   // slot in [0, SETPAD)
    const float* s = (set < 2 ? pred : gt) + (set & 1) * IMG;
    float r = 0.f, c = 0.f;
    bool valid = false;
    if (idx < NPTS) {
      if (idx < NV) {
        int i = idx / WW, j = idx - i * WW;
        float v1 = s[i * WW + j], v2 = s[(i + 1) * WW + j];
        c = (float)j;
        if (v1 == 0.f)      { r = (float)i;       valid = true; }
        else if (v2 == 0.f) { r = (float)i + 1.f; valid = true; }
        else {
          r = (float)i + fabsf(v1) / (fabsf(v1) + fabsf(v2) + EPSF);
          valid = (v1 * v2 < 0.f);
        }
      } else {
        int t = idx - NV;
        int i = t / (WW - 1), j = t - i * (WW - 1);
        float h1 = s[i * WW + j], h2 = s[i * WW + j + 1];
        r = (float)i;
        if (h1 == 0.f)      { c = (float)j;       valid = true; }
        else if (h2 == 0.f) { c = (float)j + 1.f; valid = true; }
        else {
          c = (float)j + fabsf(h1) / (fabsf(h1) + fabsf(h2) + EPSF);
          valid = (h1 * h2 < 0.f);
        }
      }
    }
    unsigned long long mask = __ballot(valid);
    int nw = __popcll(mask);
    if (lane == 0) wc[wid] = nw;
    __syncthreads();
    if (tid == 0) {
      int t0 = wc[0], t1 = wc[1], t2 = wc[2], t3 = wc[3];
      int tot = t0 + t1 + t2 + t3;
      int base = tot ? atomicAdd(&cnt[set * CNT_STRIDE], tot) : 0;
      wo[0] = base; wo[1] = base + t0; wo[2] = base + t0 + t1;
      wo[3] = base + t0 + t1 + t2;
    }
    __syncthreads();
    if (valid) {
      int lpos = __popcll(mask & ((1ull << lane) - 1ull));
      pts[set * NPTS + wo[wid] + lpos] =
          make_float4(r, c, fmaf(r, r, c * c), 0.f);
    }
  } else {
    int p = (blockIdx.x - EXBLOCKS) * 256 + tid;
    float d = fabsf(pred[p] - gt[p]);
    long long q = (long long)(d * QSCALE + 0.5f);
    q = wave_reduce_ll(q);
    if (lane == 0) rl[wid] = q;
    __syncthreads();
    if (tid == 0)
      atomicAdd(pix_i, (unsigned long long)(rl[0] + rl[1] + rl[2] + rl[3]));
  }
}

// --------------------------------------------------------------- k_min
// dir 0: A=0 B=2 | 1: A=2 B=0 | 2: A=1 B=3 | 3: A=3 B=1
// min over b of (q2 - 2px*qx - 2py*qy); +p2 and sqrt are monotone (sqrt in k_fin).
// LDS-FREE: B-slice read directly from global with block-uniform addresses
// (compiler scalarizes to s_load_dwordx4; worst case L1 broadcast). No
// staging pass, no __syncthreads. Inner math identical to r11 (pk_fma+min3).
// Epilogue keeps r14's test-and-test-and-set atomicMin (correct, never worse).
__global__ void __launch_bounds__(BLK) k_min(
    const float4* __restrict__ pts, float* __restrict__ minarr,
    const int* __restrict__ cnt) {
  int dir = blockIdx.z;
  int Aset = ((dir & 1) << 1) | (dir >> 1);
  int Bset = Aset ^ 2;
  int cntA = cnt[Aset * CNT_STRIDE], cntB = cnt[Bset * CNT_STRIDE];

  int abase0 = blockIdx.x * ACHUNK;
  if (abase0 >= cntA) return;
  int slicelen = (((cntB + NSLICE - 1) / NSLICE) + 1) & ~1;
  int b0 = blockIdx.y * slicelen;
  if (b0 >= cntB) return;
  int n = min(slicelen, cntB - b0);

  int abase = abase0 + threadIdx.x;
  f32x2 nxv[APT], nyv[APT];
  float p2v[APT], m[APT];
#pragma unroll
  for (int i = 0; i < APT; ++i) {
    int a = abase + i * BLK;
    float4 p = (a < cntA) ? pts[Aset * NPTS + a]
                          : make_float4(0.f, 0.f, 0.f, 0.f);
    float nx = -2.f * p.x, ny = -2.f * p.y;
    nxv[i].x = nx; nxv[i].y = nx;
    nyv[i].x = ny; nyv[i].y = ny;
    p2v[i] = p.z;
    m[i] = 3.0e38f;
  }

  const float4* __restrict__ bp = pts + Bset * NPTS + b0;
  int np2 = n >> 1;
#pragma unroll 2
  for (int p = 0; p < np2; ++p) {
    float4 b0v = bp[2 * p];       // block-uniform -> scalar loads
    float4 b1v = bp[2 * p + 1];
    f32x2 qx, qy, q2;
    qx.x = b0v.x; qx.y = b1v.x;
    qy.x = b0v.y; qy.y = b1v.y;
    q2.x = b0v.z; q2.y = b1v.z;
#pragma unroll
    for (int i = 0; i < APT; ++i) {
      f32x2 u = __builtin_elementwise_fma(
          nyv[i], qy, __builtin_elementwise_fma(nxv[i], qx, q2));
      m[i] = fminf(fminf(u.x, u.y), m[i]);   // -> v_min3_f32
    }
  }
  if (n & 1) {
    float4 bl = bp[n - 1];
#pragma unroll
    for (int i = 0; i < APT; ++i) {
      float t = fmaf(nyv[i].x, bl.y, fmaf(nxv[i].x, bl.x, bl.z));
      m[i] = fminf(t, m[i]);
    }
  }

#pragma unroll
  for (int i = 0; i < APT; ++i) {
    int a = abase + i * BLK;
    if (a < cntA) {
      float d2 = fmaxf(m[i] + p2v[i], 0.f);
      unsigned int mine = __float_as_uint(d2);
      unsigned int* addr = (unsigned int*)&minarr[Aset * NPTS + a];
      unsigned int cur = __hip_atomic_load(addr, __ATOMIC_RELAXED,
                                           __HIP_MEMORY_SCOPE_AGENT);
      // non-negative floats order as uint bit patterns; min is order-exact
      if (mine < cur) atomicMin(addr, mine);
    }
  }
}

// --------------------------------------------------------------- k_fin
// 32 blocks (8 chunks per set): fixed 7-trip predicated-unrolled loads (all
// in flight), then sqrt + exact int64 sums (commutative -> bit-stable),
// device atomicAdd + 32-fence ticket combine (proven cheap at this count).
__global__ void __launch_bounds__(256) k_fin(
    const float* __restrict__ minarr, const int* __restrict__ cnt,
    const unsigned long long* __restrict__ pix_i,
    unsigned long long* __restrict__ sum_i,
    unsigned int* __restrict__ ticket, float* __restrict__ out) {
  int set = blockIdx.x >> 3, q = blockIdx.x & 7;
  int tid = threadIdx.x, lane = tid & 63;
  int n = cnt[set * CNT_STRIDE];
  const float* base = minarr + set * NPTS;

  float v[FTRIPS];
#pragma unroll
  for (int k = 0; k < FTRIPS; ++k) {
    int a = q * 256 + tid + k * 2048;
    v[k] = (a < n) ? base[a] : -1.f;     // sentinel: skipped below
  }
  long long ls = 0;
#pragma unroll
  for (int k = 0; k < FTRIPS; ++k) {
    if (v[k] >= 0.f) ls += (long long)(sqrtf(v[k]) * QSCALE + 0.5f);
  }
  ls = wave_reduce_ll(ls);
  if (lane == 0) atomicAdd(&sum_i[set], (unsigned long long)ls);
  __syncthreads();

  if (tid == 0) {
    __threadfence();
    unsigned int t = atomicAdd(ticket, 1u);
    if (t == FINB - 1) {  // all blocks' adds complete (device-scope atomics)
      const float iq = 1.0f / QSCALE;
      float ss[4];
      for (int k = 0; k < 4; ++k)
        ss[k] = (float)((long long)atomicAdd(&sum_i[k], 0ull)) * iq;
      float n0 = fmaxf((float)cnt[0 * CNT_STRIDE], 1.f);
      float n1 = fmaxf((float)cnt[1 * CNT_STRIDE], 1.f);
      float n2 = fmaxf((float)cnt[2 * CNT_STRIDE], 1.f);
      float n3 = fmaxf((float)cnt[3 * CNT_STRIDE], 1.f);
      float ch0 = -ss[0] / n0 + ss[2] / n2;
      float ch1 = -ss[1] / n1 + ss[3] / n3;
      out[0] = (float)(long long)(*pix_i) * iq / (float)NPIX;
      out[1] = 0.5f * (ch0 + ch1);
    }
  }
}

extern "C" void kernel_launch(void* const* d_in, const int* in_sizes, int n_in,
                              void* d_out, int out_size, void* d_ws, size_t ws_size,
                              hipStream_t stream) {
  const float* pred = (const float*)d_in[0];
  const float* gt   = (const float*)d_in[1];
  float* out = (float*)d_out;

  // ws: [0..1023] scalars (zeroed by k_zero) | 4*NPTS float4 pts | 4*NPTS float mins
  int* cnt = (int*)d_ws;                                                // lines @0,128,256,384
  unsigned long long* pix_i = (unsigned long long*)((char*)d_ws + PIX_OFF);
  unsigned int* ticket = (unsigned int*)((char*)d_ws + TICKET_OFF);
  unsigned long long* sum_i = (unsigned long long*)((char*)d_ws + SUM_OFF);
  float4* pts   = (float4*)((char*)d_ws + SCALAR_BYTES);
  float* minarr = (float*)((char*)d_ws + SCALAR_BYTES + sizeof(float4) * 4 * NPTS);

  k_zero<<<1, 256, 0, stream>>>((unsigned int*)d_ws);
  k_prep<<<PREPB, 256, 0, stream>>>(pred, gt, pts, minarr, cnt, pix_i);
  k_min<<<dim3(ABLOCKS, NSLICE, 4), BLK, 0, stream>>>(pts, minarr, cnt);
  k_fin<<<FINB, 256, 0, stream>>>(minarr, cnt, pix_i, sum_i, ticket, out);
}

// Round 16
// 38.751 us; speedup vs baseline: 1.1478x; 1.1478x over previous
//
#include <hip/hip_runtime.h>

#define HH 80
#define WW 80
#define IMG (HH * WW)             // 6400
#define NV ((HH - 1) * WW)        // 6320 vertical edge slots
#define NPTS (NV + HH * (WW - 1)) // 12640 edge slots per image
#define NPIX (2 * IMG)            // 12800
#define BIGF 1.0e10f
#define INVC 1.0e7f
#define EPSF 1e-8f
#define QSCALE 131072.0f          // 2^17 fixed point (exact-commutative sums)

// k_prep geometry: each set padded to 12800 slots = 50 blocks x 256 threads
#define SETPAD 12800
#define SBLOCKS (SETPAD / 256)    // 50 blocks per set
#define EXBLOCKS (4 * SBLOCKS)    // 200 extraction blocks
#define PXBLOCKS (NPIX / 256)     // 50 pixel blocks
#define PREPB (EXBLOCKS + PXBLOCKS) // 250

// k_min geometry: APT=8 (r11-proven), NSLICE=64 doubles active blocks
// 512 -> 1024 (2 -> 4 waves/SIMD) — k_min is latency-bound (r15 evidence).
#define BLK 256                   // 4 waves
#define APT 8                     // A points per thread
#define ACHUNK (BLK * APT)        // 2048
#define ABLOCKS ((NPTS + ACHUNK - 1) / ACHUNK) // 7 worst case; 4 active
#define NSLICE 64
#define MAXSLICE ((((NPTS + NSLICE - 1) / NSLICE) + 1) & ~1) // 198
#define MAXP2 (MAXSLICE / 2)      // 99 f32x2 pairs

// scalar ws layout (each contended counter on its own 128-B line)
#define CNT_STRIDE 32             // ints; cnt[set] at d_ws + set*128
#define PIX_OFF 512
#define TICKET_OFF 640
#define SUM_OFF 768               // 4 x u64
#define SCALAR_BYTES 1024

typedef float f32x2 __attribute__((ext_vector_type(2)));

__device__ __forceinline__ long long wave_reduce_ll(long long v) {
#pragma unroll
  for (int o = 32; o > 0; o >>= 1) {
    int2 p = *(int2*)&v;
    p.x = __shfl_down(p.x, o, 64);
    p.y = __shfl_down(p.y, o, 64);
    v += *(long long*)&p;
  }
  return v;
}

// --------------------------------------------------------------- k_zero
__global__ void k_zero(unsigned int* __restrict__ w) {
  w[threadIdx.x] = 0u;   // 256 threads x 4 B = 1024 B (cnt, pix, ticket, sum_i)
}

// --------------------------------------------------------------- k_prep
// 250 blocks. minarr init + (blocks 0..199) zero-crossing extraction with
// block-aggregated atomic append (one atomicAdd per block, counters on
// separate cache lines) + (blocks 200..249) pixel loss in exact int64.
// Append ORDER is non-deterministic, but all consumers are order-invariant
// and exact (multiset min; int64 sums) -> output bitwise stable.
__global__ void __launch_bounds__(256) k_prep(
    const float* __restrict__ pred, const float* __restrict__ gt,
    float2* __restrict__ pts, float* __restrict__ minarr,
    int* __restrict__ cnt, unsigned long long* __restrict__ pix_i) {
  __shared__ int wc[4], wo[4];
  __shared__ long long rl[4];
  int tid = threadIdx.x, lane = tid & 63, wid = tid >> 6;
  int gtid = blockIdx.x * 256 + tid;

  if (gtid < 4 * NPTS) minarr[gtid] = BIGF;

  if (blockIdx.x < EXBLOCKS) {
    int set = blockIdx.x / SBLOCKS;
    int idx = (blockIdx.x % SBLOCKS) * 256 + tid;   // slot in [0, SETPAD)
    const float* s = (set < 2 ? pred : gt) + (set & 1) * IMG;
    float r = 0.f, c = 0.f;
    bool valid = false;
    if (idx < NPTS) {
      if (idx < NV) {
        int i = idx / WW, j = idx - i * WW;
        float v1 = s[i * WW + j], v2 = s[(i + 1) * WW + j];
        c = (float)j;
        if (v1 == 0.f)      { r = (float)i;       valid = true; }
        else if (v2 == 0.f) { r = (float)i + 1.f; valid = true; }
        else {
          r = (float)i + fabsf(v1) / (fabsf(v1) + fabsf(v2) + EPSF);
          valid = (v1 * v2 < 0.f);
        }
      } else {
        int t = idx - NV;
        int i = t / (WW - 1), j = t - i * (WW - 1);
        float h1 = s[i * WW + j], h2 = s[i * WW + j + 1];
        r = (float)i;
        if (h1 == 0.f)      { c = (float)j;       valid = true; }
        else if (h2 == 0.f) { c = (float)j + 1.f; valid = true; }
        else {
          c = (float)j + fabsf(h1) / (fabsf(h1) + fabsf(h2) + EPSF);
          valid = (h1 * h2 < 0.f);
        }
      }
    }
    unsigned long long mask = __ballot(valid);
    int nw = __popcll(mask);
    if (lane == 0) wc[wid] = nw;
    __syncthreads();
    if (tid == 0) {
      int t0 = wc[0], t1 = wc[1], t2 = wc[2], t3 = wc[3];
      int tot = t0 + t1 + t2 + t3;
      int base = tot ? atomicAdd(&cnt[set * CNT_STRIDE], tot) : 0;
      wo[0] = base; wo[1] = base + t0; wo[2] = base + t0 + t1;
      wo[3] = base + t0 + t1 + t2;
    }
    __syncthreads();
    if (valid) {
      int lpos = __popcll(mask & ((1ull << lane) - 1ull));
      pts[set * NPTS + wo[wid] + lpos] = make_float2(r, c);
    }
  } else {
    int p = (blockIdx.x - EXBLOCKS) * 256 + tid;
    float d = fabsf(pred[p] - gt[p]);
    long long q = (long long)(d * QSCALE + 0.5f);
    q = wave_reduce_ll(q);
    if (lane == 0) rl[wid] = q;
    __syncthreads();
    if (tid == 0)
      atomicAdd(pix_i, (unsigned long long)(rl[0] + rl[1] + rl[2] + rl[3]));
  }
}

// --------------------------------------------------------------- k_min
// dir 0: A=0 B=2 | 1: A=2 B=0 | 2: A=1 B=3 | 3: A=3 B=1
// min over b of (q2 - 2px*qx - 2py*qy); +p2 and sqrt are monotone (sqrt in k_fin).
// r11 structure (LDS staging + pk_fma + min3); NSLICE=64 for 4 waves/SIMD.
// Epilogue: test-and-test-and-set atomicMin (r14-proven; values only decrease
// from BIGF, a read value is a committed upper bound -> skip never loses).
__global__ void __launch_bounds__(BLK) k_min(
    const float2* __restrict__ pts, float* __restrict__ minarr,
    const int* __restrict__ cnt) {
  int dir = blockIdx.z;
  int Aset = ((dir & 1) << 1) | (dir >> 1);
  int Bset = Aset ^ 2;
  int cntA = cnt[Aset * CNT_STRIDE], cntB = cnt[Bset * CNT_STRIDE];

  int abase0 = blockIdx.x * ACHUNK;
  if (abase0 >= cntA) return;
  int slicelen = (((cntB + NSLICE - 1) / NSLICE) + 1) & ~1;
  int b0 = blockIdx.y * slicelen;
  if (b0 >= cntB) return;
  int n = min(slicelen, cntB - b0);
  int sn = (n + 1) & ~1;  // pad to even with a dummy far point

  __shared__ f32x2 qx_s[MAXP2], qy_s[MAXP2], q2_s[MAXP2];
  for (int i = threadIdx.x; i < sn; i += BLK) {
    float2 q = (i < n) ? pts[Bset * NPTS + b0 + i] : make_float2(INVC, INVC);
    ((float*)qx_s)[i] = q.x;
    ((float*)qy_s)[i] = q.y;
    ((float*)q2_s)[i] = fmaf(q.x, q.x, q.y * q.y);
  }
  __syncthreads();

  int abase = abase0 + threadIdx.x;
  f32x2 nxv[APT], nyv[APT];
  float p2v[APT], m[APT];
#pragma unroll
  for (int i = 0; i < APT; ++i) {
    int a = abase + i * BLK;
    float2 p = (a < cntA) ? pts[Aset * NPTS + a] : make_float2(0.f, 0.f);
    float nx = -2.f * p.x, ny = -2.f * p.y;
    nxv[i].x = nx; nxv[i].y = nx;
    nyv[i].x = ny; nyv[i].y = ny;
    p2v[i] = fmaf(p.x, p.x, p.y * p.y);
    m[i] = 3.0e38f;
  }

  int np2 = sn >> 1;
#pragma unroll 2
  for (int p = 0; p < np2; ++p) {
    f32x2 qx = qx_s[p], qy = qy_s[p], q2 = q2_s[p];
#pragma unroll
    for (int i = 0; i < APT; ++i) {
      f32x2 u = __builtin_elementwise_fma(
          nyv[i], qy, __builtin_elementwise_fma(nxv[i], qx, q2));
      m[i] = fminf(fminf(u.x, u.y), m[i]);   // -> v_min3_f32
    }
  }

#pragma unroll
  for (int i = 0; i < APT; ++i) {
    int a = abase + i * BLK;
    if (a < cntA) {
      float d2 = fmaxf(m[i] + p2v[i], 0.f);
      unsigned int mine = __float_as_uint(d2);
      unsigned int* addr = (unsigned int*)&minarr[Aset * NPTS + a];
      unsigned int cur = __hip_atomic_load(addr, __ATOMIC_RELAXED,
                                           __HIP_MEMORY_SCOPE_AGENT);
      // non-negative floats order as uint bit patterns; min is order-exact
      if (mine < cur) atomicMin(addr, mine);
    }
  }
}

// --------------------------------------------------------------- k_fin
// 16 blocks (4 per set): exact int64 partial sums of round(sqrt(d2)*2^17),
// device-scope atomicAdd (order-independent, bit-exact). Ticketed last block
// combines and writes the two outputs. 16 device fences total = cheap.
__global__ void __launch_bounds__(256) k_fin(
    const float* __restrict__ minarr, const int* __restrict__ cnt,
    const unsigned long long* __restrict__ pix_i,
    unsigned long long* __restrict__ sum_i,
    unsigned int* __restrict__ ticket, float* __restrict__ out) {
  int set = blockIdx.x >> 2, q = blockIdx.x & 3;
  int tid = threadIdx.x, lane = tid & 63;
  int n = cnt[set * CNT_STRIDE];

  long long ls = 0;
  for (int i = q * 256 + tid; i < n; i += 1024) {
    float d = sqrtf(minarr[set * NPTS + i]);
    ls += (long long)(d * QSCALE + 0.5f);
  }
  ls = wave_reduce_ll(ls);
  if (lane == 0) atomicAdd(&sum_i[set], (unsigned long long)ls);
  __syncthreads();

  if (tid == 0) {
    __threadfence();
    unsigned int t = atomicAdd(ticket, 1u);
    if (t == 15u) {  // all 16 blocks' adds complete (device-scope atomics)
      const float iq = 1.0f / QSCALE;
      float ss[4];
      for (int k = 0; k < 4; ++k)
        ss[k] = (float)((long long)atomicAdd(&sum_i[k], 0ull)) * iq;
      float n0 = fmaxf((float)cnt[0 * CNT_STRIDE], 1.f);
      float n1 = fmaxf((float)cnt[1 * CNT_STRIDE], 1.f);
      float n2 = fmaxf((float)cnt[2 * CNT_STRIDE], 1.f);
      float n3 = fmaxf((float)cnt[3 * CNT_STRIDE], 1.f);
      float ch0 = -ss[0] / n0 + ss[2] / n2;
      float ch1 = -ss[1] / n1 + ss[3] / n3;
      out[0] = (float)(long long)(*pix_i) * iq / (float)NPIX;
      out[1] = 0.5f * (ch0 + ch1);
    }
  }
}

extern "C" void kernel_launch(void* const* d_in, const int* in_sizes, int n_in,
                              void* d_out, int out_size, void* d_ws, size_t ws_size,
                              hipStream_t stream) {
  const float* pred = (const float*)d_in[0];
  const float* gt   = (const float*)d_in[1];
  float* out = (float*)d_out;

  // ws: [0..1023] scalars (zeroed by k_zero) | 4*NPTS float2 pts | 4*NPTS float mins
  int* cnt = (int*)d_ws;                                                // lines @0,128,256,384
  unsigned long long* pix_i = (unsigned long long*)((char*)d_ws + PIX_OFF);
  unsigned int* ticket = (unsigned int*)((char*)d_ws + TICKET_OFF);
  unsigned long long* sum_i = (unsigned long long*)((char*)d_ws + SUM_OFF);
  float2* pts   = (float2*)((char*)d_ws + SCALAR_BYTES);
  float* minarr = (float*)((char*)d_ws + SCALAR_BYTES + sizeof(float2) * 4 * NPTS);

  k_zero<<<1, 256, 0, stream>>>((unsigned int*)d_ws);
  k_prep<<<PREPB, 256, 0, stream>>>(pred, gt, pts, minarr, cnt, pix_i);
  k_min<<<dim3(ABLOCKS, NSLICE, 4), BLK, 0, stream>>>(pts, minarr, cnt);
  k_fin<<<16, 256, 0, stream>>>(minarr, cnt, pix_i, sum_i, ticket, out);
}